// Round 11
// baseline (163.762 us; speedup 1.0000x reference)
//
#include <hip/hip_runtime.h>
#include <hip/hip_bf16.h>
#include <cstdint>
#include <cstddef>

constexpr int BB = 64;
constexpr int NN = 1024;
constexpr int DD = 256;
constexpr int PP = 256;

typedef short short8 __attribute__((ext_vector_type(8)));
typedef float f32x4 __attribute__((ext_vector_type(4)));

constexpr float LOG2E = 1.4426950408889634f;

__device__ __forceinline__ unsigned short f2bf(float f) {
    union { __hip_bfloat16 h; unsigned short u; } v;
    v.h = __float2bfloat16(f);
    return v.u;
}

// fast sigmoid: rcp(1 + exp2(-x*log2e)) — 4 VALU instrs, vs ~10 for 1/(1+expf)
__device__ __forceinline__ float fsigmoid(float x) {
    return __builtin_amdgcn_rcpf(1.f + __builtin_amdgcn_exp2f(x * -LOG2E));
}

// async global->LDS, 16B per lane, LDS dest = wave-uniform base + lane*16
__device__ __forceinline__ void async_load16(void* lds, const void* g) {
    __builtin_amdgcn_global_load_lds(
        (const __attribute__((address_space(1))) unsigned int*)g,
        (__attribute__((address_space(3))) unsigned int*)lds, 16, 0, 0);
}

// Read a 16B MFMA fragment from a swizzled tile (row-stride 512B).
__device__ __forceinline__ short8 lds_frag(const unsigned short* lds, int row, int kidx) {
    uint32_t byte = (uint32_t)(row * 512) + (uint32_t)(((kidx ^ (row & 7)) & 31) << 4);
    return *reinterpret_cast<const short8*>(reinterpret_cast<const char*>(lds) + byte);
}

// ---- prep: wt[j][d] = bf16(w[d][j]) for j<256 -> w1, else w2 (transposed, bf16) ----
__global__ void prep_wt(const float* __restrict__ w1, const float* __restrict__ w2,
                        unsigned short* __restrict__ wt) {
    int j = blockIdx.x;        // 0..511
    int d = threadIdx.x;       // 0..255
    const float* w = (j < PP) ? w1 : w2;
    int jj = j & (PP - 1);
    wt[j * DD + d] = f2bf(w[d * PP + jj]);
}

// ---- q,k = sigmoid(x @ W)  +  xv = x @ w4, fused ----
// 256-thr blocks (4 waves), grid 1024 x-tiles of 64 rows. x staged ONCE into
// 32KB swizzled LDS + ONE barrier -> 4 blocks/CU: preambles (HBM x reads)
// overlap other blocks' MFMA. Four 128-col chunks: chunk h covers wt rows
// [h*128, h*128+128) (h<2 -> q, else k), wave owns 32 cols per chunk.
// FULL coverage with 4 waves: 4 chunks x 4 waves x 32 = 512 wt rows.
__global__ __launch_bounds__(256, 4) void qk_fused(const float* __restrict__ x,
                                                   const unsigned short* __restrict__ wt,
                                                   const float* __restrict__ w4,
                                                   unsigned short* __restrict__ qb,
                                                   unsigned short* __restrict__ kb,
                                                   float* __restrict__ xv) {
    __shared__ __align__(16) unsigned short xs[64 * 256];   // 32KB, swizzled
    const int t = threadIdx.x, wv = t >> 6, lane = t & 63, l15 = lane & 15, l4 = lane >> 4;
    const int xbase = blockIdx.x * 64;

    // preamble: stage x rows (f32 -> bf16, write-side swizzle) + xv dot
    {
        const int row = t >> 2, cb = t & 3;     // row 0..63, col-block of 64
        const float* xr = x + (size_t)(xbase + row) * DD + cb * 64;
        const float* w4r = w4 + cb * 64;
        float xvp = 0.f;
        #pragma unroll
        for (int j = 0; j < 8; j++) {
            float4 a = *reinterpret_cast<const float4*>(xr + j * 8);
            float4 bq = *reinterpret_cast<const float4*>(xr + j * 8 + 4);
            float4 wa = *reinterpret_cast<const float4*>(w4r + j * 8);
            float4 wb = *reinterpret_cast<const float4*>(w4r + j * 8 + 4);
            xvp += a.x * wa.x + a.y * wa.y + a.z * wa.z + a.w * wa.w
                 + bq.x * wb.x + bq.y * wb.y + bq.z * wb.z + bq.w * wb.w;
            short8 f;
            f[0] = (short)f2bf(a.x);  f[1] = (short)f2bf(a.y);
            f[2] = (short)f2bf(a.z);  f[3] = (short)f2bf(a.w);
            f[4] = (short)f2bf(bq.x); f[5] = (short)f2bf(bq.y);
            f[6] = (short)f2bf(bq.z); f[7] = (short)f2bf(bq.w);
            int blk = cb * 8 + j;
            uint32_t byte = (uint32_t)(row * 512) + (uint32_t)((blk ^ (row & 7)) << 4);
            *reinterpret_cast<short8*>(reinterpret_cast<char*>(xs) + byte) = f;
        }
        xvp += __shfl_xor(xvp, 1);
        xvp += __shfl_xor(xvp, 2);
        if (cb == 0) xv[xbase + row] = xvp;
    }
    __syncthreads();   // the only barrier

    #pragma unroll 1
    for (int h = 0; h < 4; h++) {
        // hoist W fragments for this wave's 32 cols of chunk h (L2-resident wt)
        short8 wf[2][8];
        #pragma unroll
        for (int pt = 0; pt < 2; pt++)
            #pragma unroll
            for (int kc = 0; kc < 8; kc++)
                wf[pt][kc] = *reinterpret_cast<const short8*>(
                    wt + (size_t)(h * 128 + wv * 32 + pt * 16 + l15) * DD + kc * 32 + l4 * 8);
        unsigned short* outp = (h < 2) ? qb : kb;
        const int colBase = (h & 1) * 128 + wv * 32;
        #pragma unroll
        for (int set = 0; set < 4; set++) {
            f32x4 acc0 = {0.f, 0.f, 0.f, 0.f};
            f32x4 acc1 = {0.f, 0.f, 0.f, 0.f};
            #pragma unroll
            for (int kc = 0; kc < 8; kc++) {
                short8 af = lds_frag(xs, set * 16 + l15, kc * 4 + l4);
                acc0 = __builtin_amdgcn_mfma_f32_16x16x32_bf16(wf[0][kc], af, acc0, 0, 0, 0);
                acc1 = __builtin_amdgcn_mfma_f32_16x16x32_bf16(wf[1][kc], af, acc1, 0, 0, 0);
            }
            // D: col(l15) = x-row, row(l4*4+r) = p-col
            ushort4 pk;
            size_t rowoff = (size_t)(xbase + set * 16 + l15) * PP + colBase;
            pk.x = f2bf(fsigmoid(acc0[0]));
            pk.y = f2bf(fsigmoid(acc0[1]));
            pk.z = f2bf(fsigmoid(acc0[2]));
            pk.w = f2bf(fsigmoid(acc0[3]));
            *reinterpret_cast<ushort4*>(outp + rowoff + l4 * 4) = pk;
            pk.x = f2bf(fsigmoid(acc1[0]));
            pk.y = f2bf(fsigmoid(acc1[1]));
            pk.z = f2bf(fsigmoid(acc1[2]));
            pk.w = f2bf(fsigmoid(acc1[3]));
            *reinterpret_cast<ushort4*>(outp + rowoff + 16 + l4 * 4) = pk;
        }
    }
}

// ---- partial logits: num/den over one m-QUARTER, all q of b ----
// 512-thr blocks (8 waves), 1-D grid 256, XCD-PINNED: wg&7 = b%8, so the 4
// quarter-blocks of each b run on ONE XCD concurrently -> q[b] (512KB) is
// fetched once into that XCD's L2 and shared. K-quarter (256 rows, 128KB
// swizzled) staged ONCE + ONE barrier; each wave runs 2 passes of 64 q-rows
// (qf[4][8]) sweeping 16 m-chunks from LDS. No per-chunk barriers.
__global__ __launch_bounds__(512, 2) void attn_logit(const unsigned short* __restrict__ qb,
                                                     const unsigned short* __restrict__ kb,
                                                     const float* __restrict__ xv,
                                                     float* __restrict__ numo,
                                                     float* __restrict__ deno) {
    __shared__ __align__(16) unsigned short kq[256 * 256];   // 128KB, swizzled
    __shared__ float xvs[256];
    const int t = threadIdx.x, wv = t >> 6, lane = t & 63, l15 = lane & 15, l4 = lane >> 4;
    // XCD-pinned decode: wg = (b%8) + 8*(quarter + 4*(b/8))
    const int wg = blockIdx.x;
    const int xcd = wg & 7, r_ = wg >> 3;
    const int quarter = r_ & 3;
    const int b = xcd + 8 * (r_ >> 2);
    const unsigned short* kbb = kb + ((size_t)b * NN + quarter * 256) * PP;

    // stage K-quarter: wave wv stages rows wv*32..+31 (pre-swizzled source)
    {
        char* dst0 = (char*)kq + wv * 16384;
        #pragma unroll
        for (int i = 0; i < 16; i++) {
            int row = wv * 32 + i * 2 + (lane >> 5);
            int blk = (lane & 31) ^ (row & 7);
            async_load16(dst0 + i * 1024, (const char*)kbb + row * 512 + blk * 16);
        }
    }
    if (t < 256) xvs[t] = xv[b * NN + quarter * 256 + t];
    __syncthreads();   // the only barrier

    #pragma unroll 1
    for (int p = 0; p < 2; p++) {
        // hoist Q fragments: 64 q-rows for this wave/pass
        short8 qf[4][8];
        const int q0 = b * NN + p * 512 + wv * 64;
        #pragma unroll
        for (int s = 0; s < 4; s++) {
            const unsigned short* qrow = qb + (size_t)(q0 + s * 16 + l15) * PP;
            #pragma unroll
            for (int kc = 0; kc < 8; kc++)
                qf[s][kc] = *reinterpret_cast<const short8*>(qrow + kc * 32 + l4 * 8);
        }
        float den[4][4], num[4][4];
        #pragma unroll
        for (int s = 0; s < 4; s++)
            #pragma unroll
            for (int r = 0; r < 4; r++) { den[s][r] = 0.f; num[s][r] = 0.f; }

        #pragma unroll 4
        for (int mc = 0; mc < 16; mc++) {
            f32x4 z = {0.f, 0.f, 0.f, 0.f};
            f32x4 a[4] = {z, z, z, z};
            #pragma unroll
            for (int kc = 0; kc < 8; kc++) {
                short8 kf = lds_frag(kq, mc * 16 + l15, kc * 4 + l4);
                a[0] = __builtin_amdgcn_mfma_f32_16x16x32_bf16(qf[0][kc], kf, a[0], 0, 0, 0);
                a[1] = __builtin_amdgcn_mfma_f32_16x16x32_bf16(qf[1][kc], kf, a[1], 0, 0, 0);
                a[2] = __builtin_amdgcn_mfma_f32_16x16x32_bf16(qf[2][kc], kf, a[2], 0, 0, 0);
                a[3] = __builtin_amdgcn_mfma_f32_16x16x32_bf16(qf[3][kc], kf, a[3], 0, 0, 0);
            }
            float xvv = xvs[mc * 16 + l15];
            #pragma unroll
            for (int s = 0; s < 4; s++)
                #pragma unroll
                for (int r = 0; r < 4; r++) {
                    // exp(s/16) = exp2(s * 0.0625*log2e); s in (0,16): no max-subtract
                    float e = __builtin_amdgcn_exp2f(a[s][r] * (0.0625f * LOG2E));
                    den[s][r] += e;
                    num[s][r] += e * xvv;
                }
        }
        // reduce over the 16 lanes (l15 group) holding different m-columns
        #pragma unroll
        for (int s = 0; s < 4; s++)
            #pragma unroll
            for (int r = 0; r < 4; r++) {
                #pragma unroll
                for (int off = 1; off < 16; off <<= 1) {
                    den[s][r] += __shfl_xor(den[s][r], off);
                    num[s][r] += __shfl_xor(num[s][r], off);
                }
            }
        if (l15 == 0) {
            #pragma unroll
            for (int s = 0; s < 4; s++)
                #pragma unroll
                for (int r = 0; r < 4; r++) {
                    int n = p * 512 + wv * 64 + s * 16 + l4 * 4 + r;
                    size_t o = (size_t)quarter * BB * NN + (size_t)b * NN + n;
                    numo[o] = num[s][r];
                    deno[o] = den[s][r];
                }
        }
    }
}

// ---- sentence partials: merge 4 num/den quarters -> softmax_n -> weighted row sum ----
__global__ __launch_bounds__(256) void sent_partial(const float* __restrict__ x,
                                                    const float* __restrict__ numo,
                                                    const float* __restrict__ deno,
                                                    float* __restrict__ part) {
    __shared__ float al[64];
    __shared__ float redA[4];
    __shared__ float redB[4];
    const int b = blockIdx.x, ch = blockIdx.y;
    const int t = threadIdx.x;
    float l[4];
    #pragma unroll
    for (int i = 0; i < 4; i++) {
        int n = b * NN + t + i * 256;
        float ns = 0.f, ds = 0.f;
        #pragma unroll
        for (int q = 0; q < 4; q++) {
            ns += numo[(size_t)q * BB * NN + n];
            ds += deno[(size_t)q * BB * NN + n];
        }
        l[i] = ns / ds;
    }
    float mx = fmaxf(fmaxf(l[0], l[1]), fmaxf(l[2], l[3]));
    #pragma unroll
    for (int off = 1; off < 64; off <<= 1) mx = fmaxf(mx, __shfl_xor(mx, off));
    if ((t & 63) == 0) redA[t >> 6] = mx;
    __syncthreads();
    mx = fmaxf(fmaxf(redA[0], redA[1]), fmaxf(redA[2], redA[3]));
    float e[4], es = 0.f;
    #pragma unroll
    for (int i = 0; i < 4; i++) { e[i] = __expf(l[i] - mx); es += e[i]; }
    #pragma unroll
    for (int off = 1; off < 64; off <<= 1) es += __shfl_xor(es, off);
    if ((t & 63) == 0) redB[t >> 6] = es;
    __syncthreads();
    float inv = 1.f / (redB[0] + redB[1] + redB[2] + redB[3]);
    int ei = ch >> 2;
    float sel = (ei == 0) ? e[0] : (ei == 1) ? e[1] : (ei == 2) ? e[2] : e[3];
    if ((t >> 6) == (ch & 3)) al[t & 63] = sel * inv;
    __syncthreads();
    float acc = 0.f;
    const float* xb = x + ((size_t)b * NN + ch * 64) * DD + t;
    #pragma unroll 8
    for (int n = 0; n < 64; n++)
        acc += al[n] * xb[(size_t)n * DD];
    part[(b * 16 + ch) * DD + t] = acc;
}

__global__ void sent_final(const float* __restrict__ part, float* __restrict__ out) {
    int b = blockIdx.x, t = threadIdx.x;
    float s = 0.f;
    #pragma unroll
    for (int c = 0; c < 16; c++) s += part[(b * 16 + c) * DD + t];
    out[b * DD + t] = s;
}

extern "C" void kernel_launch(void* const* d_in, const int* in_sizes, int n_in,
                              void* d_out, int out_size, void* d_ws, size_t ws_size,
                              hipStream_t stream) {
    (void)in_sizes; (void)n_in; (void)out_size; (void)ws_size;
    const float* x  = (const float*)d_in[0];
    const float* w1 = (const float*)d_in[1];
    const float* w2 = (const float*)d_in[2];
    const float* w4 = (const float*)d_in[3];
    float* out = (float*)d_out;

    char* ws = (char*)d_ws;
    const size_t MB = 1024 * 1024;
    unsigned short* qb   = (unsigned short*)(ws);                    // 32 MB
    unsigned short* kb   = (unsigned short*)(ws + 32 * MB);          // 32 MB
    unsigned short* wt   = (unsigned short*)(ws + 64 * MB);          // 256 KB
    float*          xv   = (float*)(ws + 64 * MB + 256 * 1024);     // 256 KB
    float*          num  = (float*)(ws + 64 * MB + 512 * 1024);     // 1 MB (4 quarters)
    float*          den  = (float*)(ws + 64 * MB + 1536 * 1024);    // 1 MB (4 quarters)
    float*          part = (float*)(ws);   // aliases qb: safe — qb fully rewritten each call

    prep_wt<<<dim3(2 * PP), dim3(DD), 0, stream>>>(w1, w2, wt);
    qk_fused<<<dim3(BB * NN / 64), dim3(256), 0, stream>>>(x, wt, w4, qb, kb, xv);
    attn_logit<<<dim3(4 * BB), dim3(512), 0, stream>>>(qb, kb, xv, num, den);
    sent_partial<<<dim3(BB, 16), dim3(256), 0, stream>>>(x, num, den, part);
    sent_final<<<dim3(BB), dim3(DD), 0, stream>>>(part, out);
}

// Round 12
// 117.064 us; speedup vs baseline: 1.3989x; 1.3989x over previous
//
#include <hip/hip_runtime.h>
#include <hip/hip_bf16.h>
#include <cstdint>
#include <cstddef>

constexpr int BB = 64;
constexpr int NN = 1024;
constexpr int DD = 256;
constexpr int PP = 256;

typedef short short8 __attribute__((ext_vector_type(8)));
typedef float f32x4 __attribute__((ext_vector_type(4)));

constexpr float LOG2E = 1.4426950408889634f;

__device__ __forceinline__ unsigned short f2bf(float f) {
    union { __hip_bfloat16 h; unsigned short u; } v;
    v.h = __float2bfloat16(f);
    return v.u;
}

// fast sigmoid: rcp(1 + exp2(-x*log2e)) — 4 VALU instrs vs ~10 for 1/(1+expf)
__device__ __forceinline__ float fsigmoid(float x) {
    return __builtin_amdgcn_rcpf(1.f + __builtin_amdgcn_exp2f(x * -LOG2E));
}

// async global->LDS, 16B per lane, LDS dest = wave-uniform base + lane*16
__device__ __forceinline__ void async_load16(void* lds, const void* g) {
    __builtin_amdgcn_global_load_lds(
        (const __attribute__((address_space(1))) unsigned int*)g,
        (__attribute__((address_space(3))) unsigned int*)lds, 16, 0, 0);
}

// Stage a 32-row x 256-col bf16 chunk (16KB), 4 waves, 4 loads each.
// XOR-swizzled via pre-swizzled SOURCE (LDS write stays linear).
__device__ __forceinline__ void stage32(const unsigned short* base,
                                        unsigned short* lds, int wv, int lane) {
    char* dst0 = (char*)lds + wv * 4096;
    #pragma unroll
    for (int i = 0; i < 4; i++) {
        int row = wv * 8 + i * 2 + (lane >> 5);
        int blk = (lane & 31) ^ (row & 7);
        async_load16(dst0 + i * 1024, (const char*)base + row * 512 + blk * 16);
    }
}

// Read a 16B MFMA fragment from a swizzled tile (row-stride 512B).
__device__ __forceinline__ short8 lds_frag(const unsigned short* lds, int row, int kidx) {
    uint32_t byte = (uint32_t)(row * 512) + (uint32_t)(((kidx ^ (row & 7)) & 31) << 4);
    return *reinterpret_cast<const short8*>(reinterpret_cast<const char*>(lds) + byte);
}

// ---- prep: wt[j][d] = bf16(w[d][j]) for j<256 -> w1, else w2 (transposed, bf16) ----
__global__ void prep_wt(const float* __restrict__ w1, const float* __restrict__ w2,
                        unsigned short* __restrict__ wt) {
    int j = blockIdx.x;        // 0..511
    int d = threadIdx.x;       // 0..255
    const float* w = (j < PP) ? w1 : w2;
    int jj = j & (PP - 1);
    wt[j * DD + d] = f2bf(w[d * PP + jj]);
}

// ---- q,k = sigmoid(x @ W)  +  xv = x @ w4, fused ----
// PROVEN structure (r5/r6, 47.8us): 256-thr blocks (4 waves), grid 512. Wave
// owns 32 x-rows in regs (xf[2][8], 64 VGPR). W streamed as 16 tiles of 32
// p-cols, dbuf 2x16KB = 32KB LDS -> 4 blocks/CU (launch_bounds cap), 16
// waves/CU. fsigmoid epilogue cuts the VALU that was 36% busy.
__global__ __launch_bounds__(256, 4) void qk_fused(const float* __restrict__ x,
                                                   const unsigned short* __restrict__ wt,
                                                   const float* __restrict__ w4,
                                                   unsigned short* __restrict__ qb,
                                                   unsigned short* __restrict__ kb,
                                                   float* __restrict__ xv) {
    __shared__ __align__(16) unsigned short wtile[2][8192];   // 2 x 16KB
    const int t = threadIdx.x, wv = t >> 6, lane = t & 63, l15 = lane & 15, l4 = lane >> 4;
    const int rowBase = blockIdx.x * 128 + wv * 32;

    stage32(wt, wtile[0], wv, lane);   // ct=0

    // hoist x fragments (bf16) + accumulate xv partials (f32)
    short8 xf[2][8];
    float xvp[2] = {0.f, 0.f};
    #pragma unroll
    for (int kc = 0; kc < 8; kc++) {
        float4 w4a = *reinterpret_cast<const float4*>(w4 + kc * 32 + l4 * 8);
        float4 w4b = *reinterpret_cast<const float4*>(w4 + kc * 32 + l4 * 8 + 4);
        #pragma unroll
        for (int s = 0; s < 2; s++) {
            const float* xr = x + (size_t)(rowBase + s * 16 + l15) * DD + kc * 32 + l4 * 8;
            float4 a = *reinterpret_cast<const float4*>(xr);
            float4 b = *reinterpret_cast<const float4*>(xr + 4);
            xvp[s] += a.x * w4a.x + a.y * w4a.y + a.z * w4a.z + a.w * w4a.w
                    + b.x * w4b.x + b.y * w4b.y + b.z * w4b.z + b.w * w4b.w;
            short8 f;
            f[0] = (short)f2bf(a.x); f[1] = (short)f2bf(a.y);
            f[2] = (short)f2bf(a.z); f[3] = (short)f2bf(a.w);
            f[4] = (short)f2bf(b.x); f[5] = (short)f2bf(b.y);
            f[6] = (short)f2bf(b.z); f[7] = (short)f2bf(b.w);
            xf[s][kc] = f;
        }
    }
    // xv: reduce over l4 (lane bits 4,5); rows are uniquely owned -> write
    #pragma unroll
    for (int s = 0; s < 2; s++) {
        xvp[s] += __shfl_xor(xvp[s], 16);
        xvp[s] += __shfl_xor(xvp[s], 32);
        if (l4 == 0) xv[rowBase + s * 16 + l15] = xvp[s];
    }

    __syncthreads();   // drains stage of ct=0
    int buf = 0;
    for (int ct = 0; ct < 16; ct++) {
        if (ct + 1 < 16) stage32(wt + (size_t)(ct + 1) * 32 * DD, wtile[buf ^ 1], wv, lane);
        unsigned short* outp = (ct < 8) ? qb : kb;
        const int pc0 = (ct & 7) * 32;
        #pragma unroll
        for (int st = 0; st < 2; st++) {
            f32x4 acc0 = {0.f, 0.f, 0.f, 0.f};
            f32x4 acc1 = {0.f, 0.f, 0.f, 0.f};
            #pragma unroll
            for (int kc = 0; kc < 8; kc++) {
                short8 wf = lds_frag(wtile[buf], st * 16 + l15, kc * 4 + l4);
                acc0 = __builtin_amdgcn_mfma_f32_16x16x32_bf16(wf, xf[0][kc], acc0, 0, 0, 0);
                acc1 = __builtin_amdgcn_mfma_f32_16x16x32_bf16(wf, xf[1][kc], acc1, 0, 0, 0);
            }
            // D: col(l15) = x-row, row(l4*4+r) = p-col -> 4 consecutive p per lane
            const int pc = pc0 + st * 16 + l4 * 4;
            ushort4 pk;
            pk.x = f2bf(fsigmoid(acc0[0]));
            pk.y = f2bf(fsigmoid(acc0[1]));
            pk.z = f2bf(fsigmoid(acc0[2]));
            pk.w = f2bf(fsigmoid(acc0[3]));
            *reinterpret_cast<ushort4*>(outp + (size_t)(rowBase + l15) * PP + pc) = pk;
            pk.x = f2bf(fsigmoid(acc1[0]));
            pk.y = f2bf(fsigmoid(acc1[1]));
            pk.z = f2bf(fsigmoid(acc1[2]));
            pk.w = f2bf(fsigmoid(acc1[3]));
            *reinterpret_cast<ushort4*>(outp + (size_t)(rowBase + 16 + l15) * PP + pc) = pk;
        }
        __syncthreads();
        buf ^= 1;
    }
}

// ---- partial logits: num/den over one m-QUARTER, all q of b ----
// 512-thr blocks (8 waves), 1-D grid 256, XCD-PINNED: wg&7 = b%8, so the 4
// quarter-blocks of each b run on ONE XCD concurrently -> q[b] (512KB) is
// fetched once into that XCD's L2 and shared. K-quarter (256 rows, 128KB
// swizzled) staged ONCE + ONE barrier; each wave runs 2 passes of 64 q-rows
// (qf[4][8]) sweeping 16 m-chunks from LDS. No per-chunk barriers.
__global__ __launch_bounds__(512, 2) void attn_logit(const unsigned short* __restrict__ qb,
                                                     const unsigned short* __restrict__ kb,
                                                     const float* __restrict__ xv,
                                                     float* __restrict__ numo,
                                                     float* __restrict__ deno) {
    __shared__ __align__(16) unsigned short kq[256 * 256];   // 128KB, swizzled
    __shared__ float xvs[256];
    const int t = threadIdx.x, wv = t >> 6, lane = t & 63, l15 = lane & 15, l4 = lane >> 4;
    // XCD-pinned decode: wg = (b%8) + 8*(quarter + 4*(b/8))
    const int wg = blockIdx.x;
    const int xcd = wg & 7, r_ = wg >> 3;
    const int quarter = r_ & 3;
    const int b = xcd + 8 * (r_ >> 2);
    const unsigned short* kbb = kb + ((size_t)b * NN + quarter * 256) * PP;

    // stage K-quarter: wave wv stages rows wv*32..+31 (pre-swizzled source)
    {
        char* dst0 = (char*)kq + wv * 16384;
        #pragma unroll
        for (int i = 0; i < 16; i++) {
            int row = wv * 32 + i * 2 + (lane >> 5);
            int blk = (lane & 31) ^ (row & 7);
            async_load16(dst0 + i * 1024, (const char*)kbb + row * 512 + blk * 16);
        }
    }
    if (t < 256) xvs[t] = xv[b * NN + quarter * 256 + t];
    __syncthreads();   // the only barrier

    #pragma unroll 1
    for (int p = 0; p < 2; p++) {
        // hoist Q fragments: 64 q-rows for this wave/pass
        short8 qf[4][8];
        const int q0 = b * NN + p * 512 + wv * 64;
        #pragma unroll
        for (int s = 0; s < 4; s++) {
            const unsigned short* qrow = qb + (size_t)(q0 + s * 16 + l15) * PP;
            #pragma unroll
            for (int kc = 0; kc < 8; kc++)
                qf[s][kc] = *reinterpret_cast<const short8*>(qrow + kc * 32 + l4 * 8);
        }
        float den[4][4], num[4][4];
        #pragma unroll
        for (int s = 0; s < 4; s++)
            #pragma unroll
            for (int r = 0; r < 4; r++) { den[s][r] = 0.f; num[s][r] = 0.f; }

        #pragma unroll 4
        for (int mc = 0; mc < 16; mc++) {
            f32x4 z = {0.f, 0.f, 0.f, 0.f};
            f32x4 a[4] = {z, z, z, z};
            #pragma unroll
            for (int kc = 0; kc < 8; kc++) {
                short8 kf = lds_frag(kq, mc * 16 + l15, kc * 4 + l4);
                a[0] = __builtin_amdgcn_mfma_f32_16x16x32_bf16(qf[0][kc], kf, a[0], 0, 0, 0);
                a[1] = __builtin_amdgcn_mfma_f32_16x16x32_bf16(qf[1][kc], kf, a[1], 0, 0, 0);
                a[2] = __builtin_amdgcn_mfma_f32_16x16x32_bf16(qf[2][kc], kf, a[2], 0, 0, 0);
                a[3] = __builtin_amdgcn_mfma_f32_16x16x32_bf16(qf[3][kc], kf, a[3], 0, 0, 0);
            }
            float xvv = xvs[mc * 16 + l15];
            #pragma unroll
            for (int s = 0; s < 4; s++)
                #pragma unroll
                for (int r = 0; r < 4; r++) {
                    // exp(s/16) = exp2(s * 0.0625*log2e); s in (0,16): no max-subtract
                    float e = __builtin_amdgcn_exp2f(a[s][r] * (0.0625f * LOG2E));
                    den[s][r] += e;
                    num[s][r] += e * xvv;
                }
        }
        // reduce over the 16 lanes (l15 group) holding different m-columns
        #pragma unroll
        for (int s = 0; s < 4; s++)
            #pragma unroll
            for (int r = 0; r < 4; r++) {
                #pragma unroll
                for (int off = 1; off < 16; off <<= 1) {
                    den[s][r] += __shfl_xor(den[s][r], off);
                    num[s][r] += __shfl_xor(num[s][r], off);
                }
            }
        if (l15 == 0) {
            #pragma unroll
            for (int s = 0; s < 4; s++)
                #pragma unroll
                for (int r = 0; r < 4; r++) {
                    int n = p * 512 + wv * 64 + s * 16 + l4 * 4 + r;
                    size_t o = (size_t)quarter * BB * NN + (size_t)b * NN + n;
                    numo[o] = num[s][r];
                    deno[o] = den[s][r];
                }
        }
    }
}

// ---- sentence partials: merge 4 num/den quarters -> softmax_n -> weighted row sum ----
__global__ __launch_bounds__(256) void sent_partial(const float* __restrict__ x,
                                                    const float* __restrict__ numo,
                                                    const float* __restrict__ deno,
                                                    float* __restrict__ part) {
    __shared__ float al[64];
    __shared__ float redA[4];
    __shared__ float redB[4];
    const int b = blockIdx.x, ch = blockIdx.y;
    const int t = threadIdx.x;
    float l[4];
    #pragma unroll
    for (int i = 0; i < 4; i++) {
        int n = b * NN + t + i * 256;
        float ns = 0.f, ds = 0.f;
        #pragma unroll
        for (int q = 0; q < 4; q++) {
            ns += numo[(size_t)q * BB * NN + n];
            ds += deno[(size_t)q * BB * NN + n];
        }
        l[i] = ns / ds;
    }
    float mx = fmaxf(fmaxf(l[0], l[1]), fmaxf(l[2], l[3]));
    #pragma unroll
    for (int off = 1; off < 64; off <<= 1) mx = fmaxf(mx, __shfl_xor(mx, off));
    if ((t & 63) == 0) redA[t >> 6] = mx;
    __syncthreads();
    mx = fmaxf(fmaxf(redA[0], redA[1]), fmaxf(redA[2], redA[3]));
    float e[4], es = 0.f;
    #pragma unroll
    for (int i = 0; i < 4; i++) { e[i] = __expf(l[i] - mx); es += e[i]; }
    #pragma unroll
    for (int off = 1; off < 64; off <<= 1) es += __shfl_xor(es, off);
    if ((t & 63) == 0) redB[t >> 6] = es;
    __syncthreads();
    float inv = 1.f / (redB[0] + redB[1] + redB[2] + redB[3]);
    int ei = ch >> 2;
    float sel = (ei == 0) ? e[0] : (ei == 1) ? e[1] : (ei == 2) ? e[2] : e[3];
    if ((t >> 6) == (ch & 3)) al[t & 63] = sel * inv;
    __syncthreads();
    float acc = 0.f;
    const float* xb = x + ((size_t)b * NN + ch * 64) * DD + t;
    #pragma unroll 8
    for (int n = 0; n < 64; n++)
        acc += al[n] * xb[(size_t)n * DD];
    part[(b * 16 + ch) * DD + t] = acc;
}

__global__ void sent_final(const float* __restrict__ part, float* __restrict__ out) {
    int b = blockIdx.x, t = threadIdx.x;
    float s = 0.f;
    #pragma unroll
    for (int c = 0; c < 16; c++) s += part[(b * 16 + c) * DD + t];
    out[b * DD + t] = s;
}

extern "C" void kernel_launch(void* const* d_in, const int* in_sizes, int n_in,
                              void* d_out, int out_size, void* d_ws, size_t ws_size,
                              hipStream_t stream) {
    (void)in_sizes; (void)n_in; (void)out_size; (void)ws_size;
    const float* x  = (const float*)d_in[0];
    const float* w1 = (const float*)d_in[1];
    const float* w2 = (const float*)d_in[2];
    const float* w4 = (const float*)d_in[3];
    float* out = (float*)d_out;

    char* ws = (char*)d_ws;
    const size_t MB = 1024 * 1024;
    unsigned short* qb   = (unsigned short*)(ws);                    // 32 MB
    unsigned short* kb   = (unsigned short*)(ws + 32 * MB);          // 32 MB
    unsigned short* wt   = (unsigned short*)(ws + 64 * MB);          // 256 KB
    float*          xv   = (float*)(ws + 64 * MB + 256 * 1024);     // 256 KB
    float*          num  = (float*)(ws + 64 * MB + 512 * 1024);     // 1 MB (4 quarters)
    float*          den  = (float*)(ws + 64 * MB + 1536 * 1024);    // 1 MB (4 quarters)
    float*          part = (float*)(ws);   // aliases qb: safe — qb fully rewritten each call

    prep_wt<<<dim3(2 * PP), dim3(DD), 0, stream>>>(w1, w2, wt);
    qk_fused<<<dim3(BB * NN / 128), dim3(256), 0, stream>>>(x, wt, w4, qb, kb, xv);
    attn_logit<<<dim3(4 * BB), dim3(512), 0, stream>>>(qb, kb, xv, num, den);
    sent_partial<<<dim3(BB, 16), dim3(256), 0, stream>>>(x, num, den, part);
    sent_final<<<dim3(BB), dim3(DD), 0, stream>>>(part, out);
}

// Round 13
// 96.208 us; speedup vs baseline: 1.7022x; 1.2168x over previous
//
#include <hip/hip_runtime.h>
#include <hip/hip_bf16.h>
#include <cstdint>
#include <cstddef>

constexpr int BB = 64;
constexpr int NN = 1024;
constexpr int DD = 256;
constexpr int PP = 256;

typedef short short8 __attribute__((ext_vector_type(8)));
typedef float f32x4 __attribute__((ext_vector_type(4)));

constexpr float LOG2E = 1.4426950408889634f;

__device__ __forceinline__ unsigned short f2bf(float f) {
    union { __hip_bfloat16 h; unsigned short u; } v;
    v.h = __float2bfloat16(f);
    return v.u;
}

// fast sigmoid: rcp(1 + exp2(-x*log2e))
__device__ __forceinline__ float fsigmoid(float x) {
    return __builtin_amdgcn_rcpf(1.f + __builtin_amdgcn_exp2f(x * -LOG2E));
}

// async global->LDS, 16B per lane, LDS dest = wave-uniform base + lane*16
__device__ __forceinline__ void async_load16(void* lds, const void* g) {
    __builtin_amdgcn_global_load_lds(
        (const __attribute__((address_space(1))) unsigned int*)g,
        (__attribute__((address_space(3))) unsigned int*)lds, 16, 0, 0);
}

// Stage a 256-row x 256-col bf16 tile (128KB) with 8 waves; wave wv stages
// rows wv*32..+31. XOR-swizzled via pre-swizzled SOURCE (LDS write linear).
__device__ __forceinline__ void stage256(const unsigned short* base,
                                         unsigned short* lds, int wv, int lane) {
    char* dst0 = (char*)lds + wv * 16384;
    #pragma unroll
    for (int i = 0; i < 16; i++) {
        int row = wv * 32 + i * 2 + (lane >> 5);
        int blk = (lane & 31) ^ (row & 7);
        async_load16(dst0 + i * 1024, (const char*)base + row * 512 + blk * 16);
    }
}

// Read a 16B MFMA fragment from a swizzled tile (row-stride 512B).
__device__ __forceinline__ short8 lds_frag(const unsigned short* lds, int row, int kidx) {
    uint32_t byte = (uint32_t)(row * 512) + (uint32_t)(((kidx ^ (row & 7)) & 31) << 4);
    return *reinterpret_cast<const short8*>(reinterpret_cast<const char*>(lds) + byte);
}

// ---- prep: wt[j][d] = bf16(w[d][j]) for j<256 -> w1, else w2 (transposed, bf16) ----
__global__ void prep_wt(const float* __restrict__ w1, const float* __restrict__ w2,
                        unsigned short* __restrict__ wt) {
    int j = blockIdx.x;        // 0..511
    int d = threadIdx.x;       // 0..255
    const float* w = (j < PP) ? w1 : w2;
    int jj = j & (PP - 1);
    wt[j * DD + d] = f2bf(w[d * PP + jj]);
}

// ---- q,k = sigmoid(x @ W)  +  xv = x @ w4, fused (attn-style stage-once) ----
// 512-thr blocks (8 waves), grid 256 = 1 block/CU. W q-half (256x256 bf16 =
// 128KB) staged ONCE into swizzled LDS while x loads into regs (xf[2][8] per
// wave, 32 rows); ONE barrier; barrier-free 16-p-tile sweep writes q; then
// re-stage k-half into the same LDS (2 barriers, ~1us bubble) and sweep k.
// x read once from HBM; W from L2/L3. Rows written back-to-back -> full
// 512B lines -> no write amplification.
__global__ __launch_bounds__(512, 2) void qk_fused(const float* __restrict__ x,
                                                   const unsigned short* __restrict__ wt,
                                                   const float* __restrict__ w4,
                                                   unsigned short* __restrict__ qb,
                                                   unsigned short* __restrict__ kb,
                                                   float* __restrict__ xv) {
    __shared__ __align__(16) unsigned short wl[256 * 256];   // 128KB, swizzled
    const int t = threadIdx.x, wv = t >> 6, lane = t & 63, l15 = lane & 15, l4 = lane >> 4;
    const int rowBase = blockIdx.x * 256 + wv * 32;

    stage256(wt, wl, wv, lane);   // q-half of W

    // hoist x fragments (bf16) + accumulate xv partials (f32) — overlaps stage
    short8 xf[2][8];
    float xvp[2] = {0.f, 0.f};
    #pragma unroll
    for (int kc = 0; kc < 8; kc++) {
        float4 w4a = *reinterpret_cast<const float4*>(w4 + kc * 32 + l4 * 8);
        float4 w4b = *reinterpret_cast<const float4*>(w4 + kc * 32 + l4 * 8 + 4);
        #pragma unroll
        for (int s = 0; s < 2; s++) {
            const float* xr = x + (size_t)(rowBase + s * 16 + l15) * DD + kc * 32 + l4 * 8;
            float4 a = *reinterpret_cast<const float4*>(xr);
            float4 b = *reinterpret_cast<const float4*>(xr + 4);
            xvp[s] += a.x * w4a.x + a.y * w4a.y + a.z * w4a.z + a.w * w4a.w
                    + b.x * w4b.x + b.y * w4b.y + b.z * w4b.z + b.w * w4b.w;
            short8 f;
            f[0] = (short)f2bf(a.x); f[1] = (short)f2bf(a.y);
            f[2] = (short)f2bf(a.z); f[3] = (short)f2bf(a.w);
            f[4] = (short)f2bf(b.x); f[5] = (short)f2bf(b.y);
            f[6] = (short)f2bf(b.z); f[7] = (short)f2bf(b.w);
            xf[s][kc] = f;
        }
    }
    #pragma unroll
    for (int s = 0; s < 2; s++) {
        xvp[s] += __shfl_xor(xvp[s], 16);
        xvp[s] += __shfl_xor(xvp[s], 32);
        if (l4 == 0) xv[rowBase + s * 16 + l15] = xvp[s];
    }

    __syncthreads();   // q-half of W ready (compiler drains vmcnt before barrier)

    #pragma unroll 1
    for (int h = 0; h < 2; h++) {
        if (h == 1) {
            __syncthreads();               // all waves done reading q-half
            stage256(wt + 256 * DD, wl, wv, lane);   // k-half of W
            __syncthreads();               // k-half ready
        }
        unsigned short* outp = h ? kb : qb;
        #pragma unroll 1
        for (int pt = 0; pt < 16; pt++) {
            f32x4 acc0 = {0.f, 0.f, 0.f, 0.f};
            f32x4 acc1 = {0.f, 0.f, 0.f, 0.f};
            #pragma unroll
            for (int kc = 0; kc < 8; kc++) {
                short8 wf = lds_frag(wl, pt * 16 + l15, kc * 4 + l4);
                acc0 = __builtin_amdgcn_mfma_f32_16x16x32_bf16(wf, xf[0][kc], acc0, 0, 0, 0);
                acc1 = __builtin_amdgcn_mfma_f32_16x16x32_bf16(wf, xf[1][kc], acc1, 0, 0, 0);
            }
            // D: col(l15) = x-row, row(l4*4+r) = p-col
            const int pc = pt * 16 + l4 * 4;
            ushort4 pk;
            pk.x = f2bf(fsigmoid(acc0[0]));
            pk.y = f2bf(fsigmoid(acc0[1]));
            pk.z = f2bf(fsigmoid(acc0[2]));
            pk.w = f2bf(fsigmoid(acc0[3]));
            *reinterpret_cast<ushort4*>(outp + (size_t)(rowBase + l15) * PP + pc) = pk;
            pk.x = f2bf(fsigmoid(acc1[0]));
            pk.y = f2bf(fsigmoid(acc1[1]));
            pk.z = f2bf(fsigmoid(acc1[2]));
            pk.w = f2bf(fsigmoid(acc1[3]));
            *reinterpret_cast<ushort4*>(outp + (size_t)(rowBase + 16 + l15) * PP + pc) = pk;
        }
    }
}

// ---- partial logits: num/den over one m-QUARTER, all q of b ----
// 512-thr blocks (8 waves), 1-D grid 256, XCD-PINNED: wg&7 = b%8, so the 4
// quarter-blocks of each b run on ONE XCD concurrently -> q[b] (512KB) is
// fetched once into that XCD's L2 and shared. K-quarter (256 rows, 128KB
// swizzled) staged ONCE + ONE barrier; each wave runs 2 passes of 64 q-rows
// (qf[4][8]) sweeping 16 m-chunks from LDS. No per-chunk barriers.
__global__ __launch_bounds__(512, 2) void attn_logit(const unsigned short* __restrict__ qb,
                                                     const unsigned short* __restrict__ kb,
                                                     const float* __restrict__ xv,
                                                     float* __restrict__ numo,
                                                     float* __restrict__ deno) {
    __shared__ __align__(16) unsigned short kq[256 * 256];   // 128KB, swizzled
    __shared__ float xvs[256];
    const int t = threadIdx.x, wv = t >> 6, lane = t & 63, l15 = lane & 15, l4 = lane >> 4;
    // XCD-pinned decode: wg = (b%8) + 8*(quarter + 4*(b/8))
    const int wg = blockIdx.x;
    const int xcd = wg & 7, r_ = wg >> 3;
    const int quarter = r_ & 3;
    const int b = xcd + 8 * (r_ >> 2);
    const unsigned short* kbb = kb + ((size_t)b * NN + quarter * 256) * PP;

    stage256(kbb, kq, wv, lane);
    if (t < 256) xvs[t] = xv[b * NN + quarter * 256 + t];
    __syncthreads();   // the only barrier

    #pragma unroll 1
    for (int p = 0; p < 2; p++) {
        // hoist Q fragments: 64 q-rows for this wave/pass
        short8 qf[4][8];
        const int q0 = b * NN + p * 512 + wv * 64;
        #pragma unroll
        for (int s = 0; s < 4; s++) {
            const unsigned short* qrow = qb + (size_t)(q0 + s * 16 + l15) * PP;
            #pragma unroll
            for (int kc = 0; kc < 8; kc++)
                qf[s][kc] = *reinterpret_cast<const short8*>(qrow + kc * 32 + l4 * 8);
        }
        float den[4][4], num[4][4];
        #pragma unroll
        for (int s = 0; s < 4; s++)
            #pragma unroll
            for (int r = 0; r < 4; r++) { den[s][r] = 0.f; num[s][r] = 0.f; }

        #pragma unroll 4
        for (int mc = 0; mc < 16; mc++) {
            f32x4 z = {0.f, 0.f, 0.f, 0.f};
            f32x4 a[4] = {z, z, z, z};
            #pragma unroll
            for (int kc = 0; kc < 8; kc++) {
                short8 kf = lds_frag(kq, mc * 16 + l15, kc * 4 + l4);
                a[0] = __builtin_amdgcn_mfma_f32_16x16x32_bf16(qf[0][kc], kf, a[0], 0, 0, 0);
                a[1] = __builtin_amdgcn_mfma_f32_16x16x32_bf16(qf[1][kc], kf, a[1], 0, 0, 0);
                a[2] = __builtin_amdgcn_mfma_f32_16x16x32_bf16(qf[2][kc], kf, a[2], 0, 0, 0);
                a[3] = __builtin_amdgcn_mfma_f32_16x16x32_bf16(qf[3][kc], kf, a[3], 0, 0, 0);
            }
            float xvv = xvs[mc * 16 + l15];
            #pragma unroll
            for (int s = 0; s < 4; s++)
                #pragma unroll
                for (int r = 0; r < 4; r++) {
                    // exp(s/16) = exp2(s * 0.0625*log2e); s in (0,16): no max-subtract
                    float e = __builtin_amdgcn_exp2f(a[s][r] * (0.0625f * LOG2E));
                    den[s][r] += e;
                    num[s][r] += e * xvv;
                }
        }
        // reduce over the 16 lanes (l15 group) holding different m-columns
        #pragma unroll
        for (int s = 0; s < 4; s++)
            #pragma unroll
            for (int r = 0; r < 4; r++) {
                #pragma unroll
                for (int off = 1; off < 16; off <<= 1) {
                    den[s][r] += __shfl_xor(den[s][r], off);
                    num[s][r] += __shfl_xor(num[s][r], off);
                }
            }
        if (l15 == 0) {
            #pragma unroll
            for (int s = 0; s < 4; s++)
                #pragma unroll
                for (int r = 0; r < 4; r++) {
                    int n = p * 512 + wv * 64 + s * 16 + l4 * 4 + r;
                    size_t o = (size_t)quarter * BB * NN + (size_t)b * NN + n;
                    numo[o] = num[s][r];
                    deno[o] = den[s][r];
                }
        }
    }
}

// ---- sentence partials: merge 4 num/den quarters -> softmax_n -> weighted row sum ----
__global__ __launch_bounds__(256) void sent_partial(const float* __restrict__ x,
                                                    const float* __restrict__ numo,
                                                    const float* __restrict__ deno,
                                                    float* __restrict__ part) {
    __shared__ float al[64];
    __shared__ float redA[4];
    __shared__ float redB[4];
    const int b = blockIdx.x, ch = blockIdx.y;
    const int t = threadIdx.x;
    float l[4];
    #pragma unroll
    for (int i = 0; i < 4; i++) {
        int n = b * NN + t + i * 256;
        float ns = 0.f, ds = 0.f;
        #pragma unroll
        for (int q = 0; q < 4; q++) {
            ns += numo[(size_t)q * BB * NN + n];
            ds += deno[(size_t)q * BB * NN + n];
        }
        l[i] = ns / ds;
    }
    float mx = fmaxf(fmaxf(l[0], l[1]), fmaxf(l[2], l[3]));
    #pragma unroll
    for (int off = 1; off < 64; off <<= 1) mx = fmaxf(mx, __shfl_xor(mx, off));
    if ((t & 63) == 0) redA[t >> 6] = mx;
    __syncthreads();
    mx = fmaxf(fmaxf(redA[0], redA[1]), fmaxf(redA[2], redA[3]));
    float e[4], es = 0.f;
    #pragma unroll
    for (int i = 0; i < 4; i++) { e[i] = __expf(l[i] - mx); es += e[i]; }
    #pragma unroll
    for (int off = 1; off < 64; off <<= 1) es += __shfl_xor(es, off);
    if ((t & 63) == 0) redB[t >> 6] = es;
    __syncthreads();
    float inv = 1.f / (redB[0] + redB[1] + redB[2] + redB[3]);
    int ei = ch >> 2;
    float sel = (ei == 0) ? e[0] : (ei == 1) ? e[1] : (ei == 2) ? e[2] : e[3];
    if ((t >> 6) == (ch & 3)) al[t & 63] = sel * inv;
    __syncthreads();
    float acc = 0.f;
    const float* xb = x + ((size_t)b * NN + ch * 64) * DD + t;
    #pragma unroll 8
    for (int n = 0; n < 64; n++)
        acc += al[n] * xb[(size_t)n * DD];
    part[(b * 16 + ch) * DD + t] = acc;
}

__global__ void sent_final(const float* __restrict__ part, float* __restrict__ out) {
    int b = blockIdx.x, t = threadIdx.x;
    float s = 0.f;
    #pragma unroll
    for (int c = 0; c < 16; c++) s += part[(b * 16 + c) * DD + t];
    out[b * DD + t] = s;
}

extern "C" void kernel_launch(void* const* d_in, const int* in_sizes, int n_in,
                              void* d_out, int out_size, void* d_ws, size_t ws_size,
                              hipStream_t stream) {
    (void)in_sizes; (void)n_in; (void)out_size; (void)ws_size;
    const float* x  = (const float*)d_in[0];
    const float* w1 = (const float*)d_in[1];
    const float* w2 = (const float*)d_in[2];
    const float* w4 = (const float*)d_in[3];
    float* out = (float*)d_out;

    char* ws = (char*)d_ws;
    const size_t MB = 1024 * 1024;
    unsigned short* qb   = (unsigned short*)(ws);                    // 32 MB
    unsigned short* kb   = (unsigned short*)(ws + 32 * MB);          // 32 MB
    unsigned short* wt   = (unsigned short*)(ws + 64 * MB);          // 256 KB
    float*          xv   = (float*)(ws + 64 * MB + 256 * 1024);     // 256 KB
    float*          num  = (float*)(ws + 64 * MB + 512 * 1024);     // 1 MB (4 quarters)
    float*          den  = (float*)(ws + 64 * MB + 1536 * 1024);    // 1 MB (4 quarters)
    float*          part = (float*)(ws);   // aliases qb: safe — qb fully rewritten each call

    prep_wt<<<dim3(2 * PP), dim3(DD), 0, stream>>>(w1, w2, wt);
    qk_fused<<<dim3(BB * NN / 256), dim3(512), 0, stream>>>(x, wt, w4, qb, kb, xv);
    attn_logit<<<dim3(4 * BB), dim3(512), 0, stream>>>(qb, kb, xv, num, den);
    sent_partial<<<dim3(BB, 16), dim3(256), 0, stream>>>(x, num, den, part);
    sent_final<<<dim3(BB), dim3(DD), 0, stream>>>(part, out);
}